// Round 2
// baseline (189.558 us; speedup 1.0000x reference)
//
#include <hip/hip_runtime.h>

// Correlation layer: in1,in2 [8,256,128,128] f32 -> out [8,81,128,128] f32
// out[b, dy*9+dx, y, x] = mean_c in1[b,c,y,x] * in2pad[b,c,y+dy,x+dx], pad=4
//
// MFMA: per (row y, 16-px x-tile, dy): D[i][j] = sum_c in1[c,x0+i]*in2p[c,y+dy,x0+j]
// j in [0,24); out(i,dx) = D[i][i+dx]/256.
// tile0 (j 0..15): one 16x16x32 MFMA per dy (9 accs).
// tile1 (j 16..23): only 8 useful cols -> pack TWO dy per MFMA via per-lane
//   B addressing: col n -> (r = w + 2P + (n>>3), j = 16 + (n&7))  (5 accs).
// Register-prefetch next chunk; raw barriers (no vmcnt drain) keep loads in flight.

#define B_  8
#define C_  256
#define H_  128
#define W_  128
#define ND  9
#define TY  8
#define TW  16
#define KC  32
#define KB  4       // KC/8
#define RR  16      // TY+8 staged rows
#define JJ  24      // staged cols
#define NITEM 3     // KB*RR*JJ / 512 staging items per thread

typedef short v8s __attribute__((ext_vector_type(8)));
typedef float v4f __attribute__((ext_vector_type(4)));

__device__ __forceinline__ unsigned short f2bf(float f) {
    union { float f; unsigned u; } v; v.f = f;
    return (unsigned short)((v.u + 0x7FFFu + ((v.u >> 16) & 1u)) >> 16);
}

// barrier WITHOUT vmcnt drain: prefetch global loads stay in flight
#define BARRIER() asm volatile("s_waitcnt lgkmcnt(0)\n\ts_barrier" ::: "memory")
#define LGKM0()   asm volatile("s_waitcnt lgkmcnt(0)" ::: "memory")

__global__ __launch_bounds__(512, 4)
void corr_mfma_kernel(const float* __restrict__ in1,
                      const float* __restrict__ in2,
                      float* __restrict__ out) {
    __shared__ __align__(16) short Blds[KB * RR * JJ * 8];   // 24 KB

    const int tid  = threadIdx.x;
    const int lane = tid & 63;
    const int w    = tid >> 6;        // wave id = row within tile
    const int x0   = blockIdx.x * TW;
    const int y0   = blockIdx.y * TY;
    const int b    = blockIdx.z;

    const int i_px = lane & 15;
    const int kb   = lane >> 4;
    const long cs  = (long)H_ * W_;   // channel stride

    // ---- per-thread staging descriptors (fixed across chunks) ----
    const float* sptr[NITEM];
    bool svalid[NITEM];
    int ldsoff[NITEM];                // in shorts
    #pragma unroll
    for (int it = 0; it < NITEM; ++it) {
        const int s   = tid + it * 512;       // 0..1535
        const int j   = s % JJ;
        const int rr  = (s / JJ) % RR;
        const int skb = s / (JJ * RR);
        const int gy  = y0 - 4 + rr;
        const int gx  = x0 - 4 + j;
        svalid[it] = ((unsigned)gy < (unsigned)H_) && ((unsigned)gx < (unsigned)W_);
        sptr[it]   = in2 + (((long)b * C_ + skb * 8) * H_ + (svalid[it] ? gy : 0)) * W_
                         + (svalid[it] ? gx : 0);
        ldsoff[it] = ((skb * RR + rr) * JJ + j) * 8;
    }
    const float* p1 = in1 + (((long)b * C_ + kb * 8) * H_ + (y0 + w)) * W_ + x0 + i_px;

    v4f acc0[ND];
    v4f acc1[5];
    #pragma unroll
    for (int d = 0; d < ND; ++d) acc0[d] = (v4f)0.0f;
    #pragma unroll
    for (int p = 0; p < 5; ++p)  acc1[p] = (v4f)0.0f;

    float cur[NITEM][8], a_cur[8];
    float nxt[NITEM][8], a_nxt[8];

    // prologue: issue chunk 0 loads
    #pragma unroll
    for (int it = 0; it < NITEM; ++it)
        #pragma unroll
        for (int e = 0; e < 8; ++e)
            cur[it][e] = sptr[it][(long)e * cs];
    #pragma unroll
    for (int e = 0; e < 8; ++e)
        a_cur[e] = p1[(long)e * cs];

    #pragma unroll
    for (int c0 = 0; c0 < C_ / KC; ++c0) {
        // convert current chunk (forces wait on cur loads only; nxt not yet issued)
        v8s pk[NITEM];
        #pragma unroll
        for (int it = 0; it < NITEM; ++it) {
            #pragma unroll
            for (int e = 0; e < 8; ++e)
                pk[it][e] = (short)f2bf(cur[it][e]);
            if (!svalid[it]) pk[it] = (v8s)0;
        }
        v8s afrag;
        #pragma unroll
        for (int e = 0; e < 8; ++e)
            afrag[e] = (short)f2bf(a_cur[e]);

        // issue next chunk's loads (stay in flight across barriers + MFMAs)
        if (c0 < C_ / KC - 1) {
            const long co = (long)(c0 + 1) * KC * cs;
            #pragma unroll
            for (int it = 0; it < NITEM; ++it)
                #pragma unroll
                for (int e = 0; e < 8; ++e)
                    nxt[it][e] = sptr[it][co + (long)e * cs];
            #pragma unroll
            for (int e = 0; e < 8; ++e)
                a_nxt[e] = p1[co + (long)e * cs];
        }

        BARRIER();   // all waves done reading Blds (chunk c0-1)
        #pragma unroll
        for (int it = 0; it < NITEM; ++it)
            *(v8s*)&Blds[ldsoff[it]] = pk[it];
        BARRIER();   // lgkmcnt(0) + s_barrier: staging visible, vmcnt NOT drained

        // tile0: 9 dy
        #pragma unroll
        for (int dy = 0; dy < ND; ++dy) {
            const int r = w + dy;
            const v8s bf = *(const v8s*)&Blds[((kb * RR + r) * JJ + i_px) * 8];
            acc0[dy] = __builtin_amdgcn_mfma_f32_16x16x32_bf16(afrag, bf, acc0[dy], 0, 0, 0);
        }
        // tile1 packed: pair P covers dy=2P (cols n<8) and dy=2P+1 (n>=8)
        #pragma unroll
        for (int P = 0; P < 5; ++P) {
            int r = w + 2 * P + (i_px >> 3);
            if (r > RR - 1) r = RR - 1;           // P=4 upper half unused
            const int j = 16 + (i_px & 7);
            const v8s bf = *(const v8s*)&Blds[((kb * RR + r) * JJ + j) * 8];
            acc1[P] = __builtin_amdgcn_mfma_f32_16x16x32_bf16(afrag, bf, acc1[P], 0, 0, 0);
        }

        // rotate prefetch regs
        if (c0 < C_ / KC - 1) {
            #pragma unroll
            for (int it = 0; it < NITEM; ++it)
                #pragma unroll
                for (int e = 0; e < 8; ++e)
                    cur[it][e] = nxt[it][e];
            #pragma unroll
            for (int e = 0; e < 8; ++e)
                a_cur[e] = a_nxt[e];
        }
    }

    // ---- epilogue: diagonal extract via wave-private LDS scratch ----
    BARRIER();                         // all waves done with Blds as B operand
    float* epw = (float*)Blds + w * (16 * 24);   // 1.5 KB per wave
    const int g = lane >> 4;

    for (int dy = 0; dy < ND; ++dy) {
        #pragma unroll
        for (int q = 0; q < 4; ++q)
            epw[(g * 4 + q) * 24 + i_px] = acc0[dy][q];
        if ((i_px >> 3) == (dy & 1)) {
            #pragma unroll
            for (int q = 0; q < 4; ++q)
                epw[(g * 4 + q) * 24 + 16 + (i_px & 7)] = acc1[dy >> 1][q];
        }
        LGKM0();                       // wave-internal write->read ordering
        #pragma unroll
        for (int rep = 0; rep < 3; ++rep) {
            const int dx = g + rep * 4;
            if (dx < 9) {
                const float v = epw[i_px * 24 + i_px + dx] * (1.0f / 256.0f);
                out[((((long)b * 81) + dy * 9 + dx) * H_ + (y0 + w)) * W_ + x0 + i_px] = v;
            }
        }
        LGKM0();                       // reads done before next dy overwrites
    }
}

extern "C" void kernel_launch(void* const* d_in, const int* in_sizes, int n_in,
                              void* d_out, int out_size, void* d_ws, size_t ws_size,
                              hipStream_t stream) {
    const float* in1 = (const float*)d_in[0];
    const float* in2 = (const float*)d_in[1];
    float* outp      = (float*)d_out;
    dim3 grid(W_ / TW, H_ / TY, B_);   // (8, 16, 8) = 1024 blocks
    corr_mfma_kernel<<<grid, 512, 0, stream>>>(in1, in2, outp);
}

// Round 3
// 131.711 us; speedup vs baseline: 1.4392x; 1.4392x over previous
//
#include <hip/hip_runtime.h>
#include <stdint.h>

// Correlation layer: in1,in2 [8,256,128,128] f32 -> out [8,81,128,128] f32
// out[b, dy*9+dx, y, x] = mean_c in1[b,c,y,x] * in2pad[b,c,y+dy,x+dx], pad=4
//
// v3: in2 staged f32 via global_load_lds (async DMA, no VGPR round-trip) into
// S[32ch][16r][24j], converted per chunk into bf16 fragment buffer F[kb][r][j][8e].
// OOB handled at convert (mask->0); DMA sources clamped (pad=4 == 16B granule).
// tile0: 9 dy MFMAs; tile1: 2 dy packed per MFMA (5 accs). A (in1) reg-prefetch.

#define B_  8
#define C_  256
#define H_  128
#define W_  128
#define ND  9
#define TY  8
#define TW  16
#define KC  32
#define KB  4                    // KC/8
#define RR  16                   // TY+8
#define JJ  24
#define NITEM 3                  // KB*RR*JJ/512 convert items per thread
#define NDMA  6                  // (KC*RR*JJ/4)/64/8 DMA issues per wave
#define CS   (H_ * W_)           // channel stride (elements)
#define NCH  (C_ / KC)           // 8 chunks

typedef short v8s __attribute__((ext_vector_type(8)));
typedef float v4f __attribute__((ext_vector_type(4)));

__device__ __forceinline__ unsigned short f2bf(float f) {
    union { float f; unsigned u; } v; v.f = f;
    return (unsigned short)((v.u + 0x7FFFu + ((v.u >> 16) & 1u)) >> 16);
}

#define WAIT_DMA_BARRIER() asm volatile("s_waitcnt vmcnt(0) lgkmcnt(0)\n\ts_barrier" ::: "memory")
#define BARRIER()          asm volatile("s_waitcnt lgkmcnt(0)\n\ts_barrier" ::: "memory")
#define LGKM0()            asm volatile("s_waitcnt lgkmcnt(0)" ::: "memory")

__device__ __forceinline__ void dma16(const float* g, void* lds) {
    __builtin_amdgcn_global_load_lds(
        (const __attribute__((address_space(1))) void*)g,
        (__attribute__((address_space(3))) void*)lds, 16, 0, 0);
}

__global__ __launch_bounds__(512, 4)
void corr_mfma_kernel(const float* __restrict__ in1,
                      const float* __restrict__ in2,
                      float* __restrict__ out) {
    __shared__ __align__(16) float S[KC * RR * JJ];      // 48 KB f32 stage
    __shared__ __align__(16) short F[KB * RR * JJ * 8];  // 24 KB bf16 frags

    const int tid  = threadIdx.x;
    const int lane = tid & 63;
    const int w    = tid >> 6;
    const int x0   = blockIdx.x * TW;
    const int y0   = blockIdx.y * TY;
    const int b    = blockIdx.z;
    const int i_px = lane & 15;
    const int kb   = lane >> 4;

    // ---- DMA descriptors: 6 issues/wave; group g -> (cc, r, jg) ----
    const float* dsrc[NDMA];
    char* ddst[NDMA];
    #pragma unroll
    for (int t = 0; t < NDMA; ++t) {
        const int q  = w * NDMA + t;          // wave-uniform issue index
        const int g  = q * 64 + lane;         // flat 16B-group index
        const int cc = g / 96;                // channel within chunk
        const int rm = g % 96;
        const int r  = rm / 6;
        const int jg = rm % 6;
        int gy = y0 - 4 + r;
        int gx = x0 - 4 + jg * 4;
        gy = gy < 0 ? 0 : (gy > H_ - 1 ? H_ - 1 : gy);
        gx = gx < 0 ? 0 : (gx > W_ - 4 ? W_ - 4 : gx);
        dsrc[t] = in2 + ((long)(b * C_ + cc) * H_ + gy) * W_ + gx;
        ddst[t] = (char*)S + q * 1024;        // wave-uniform LDS base
    }

    // ---- convert-pass descriptors (3 items/thread) ----
    int soff[NITEM], foff[NITEM];
    bool valid[NITEM];
    #pragma unroll
    for (int it = 0; it < NITEM; ++it) {
        const int s   = tid + it * 512;       // 0..1535
        const int ikb = s / (RR * JJ);
        const int ir  = (s / JJ) % RR;
        const int ij  = s % JJ;
        soff[it]  = ikb * 8 * (RR * JJ) + ir * JJ + ij;   // dwords, +e*RR*JJ
        foff[it]  = s * 8;                                // shorts
        valid[it] = ((unsigned)(y0 - 4 + ir) < (unsigned)H_) &&
                    ((unsigned)(x0 - 4 + ij) < (unsigned)W_);
    }

    const float* p1 =
        in1 + (((long)b * C_ + kb * 8) * H_ + (y0 + w)) * W_ + x0 + i_px;

    v4f acc0[ND];
    v4f acc1[5];
    #pragma unroll
    for (int d = 0; d < ND; ++d) acc0[d] = (v4f)0.0f;
    #pragma unroll
    for (int p = 0; p < 5; ++p)  acc1[p] = (v4f)0.0f;

    // ---- prologue: DMA chunk 0 + A loads chunk 0 ----
    #pragma unroll
    for (int t = 0; t < NDMA; ++t) dma16(dsrc[t], ddst[t]);
    float a_cur[8], a_nxt[8];
    #pragma unroll
    for (int e = 0; e < 8; ++e) a_cur[e] = p1[(long)e * CS];

    #pragma unroll
    for (int k = 0; k < NCH; ++k) {
        WAIT_DMA_BARRIER();   // DMA(k) landed; prev MFMA reads of F drained

        // ---- convert S (f32) -> F (bf16, fragment order) ----
        v8s pk[NITEM];
        #pragma unroll
        for (int it = 0; it < NITEM; ++it) {
            #pragma unroll
            for (int e = 0; e < 8; ++e)
                pk[it][e] = (short)f2bf(S[soff[it] + e * (RR * JJ)]);
            if (!valid[it]) pk[it] = (v8s)0;
        }
        #pragma unroll
        for (int it = 0; it < NITEM; ++it)
            *(v8s*)&F[foff[it]] = pk[it];

        BARRIER();            // F ready; S fully consumed

        // ---- issue DMA chunk k+1 (drains under MFMAs) + A prefetch ----
        if (k < NCH - 1) {
            const long co = (long)(k + 1) * KC * CS;
            #pragma unroll
            for (int t = 0; t < NDMA; ++t) dma16(dsrc[t] + co, ddst[t]);
            #pragma unroll
            for (int e = 0; e < 8; ++e) a_nxt[e] = p1[co + (long)e * CS];
        }

        v8s afrag;
        #pragma unroll
        for (int e = 0; e < 8; ++e) afrag[e] = (short)f2bf(a_cur[e]);

        // tile0: 9 dy
        #pragma unroll
        for (int dy = 0; dy < ND; ++dy) {
            const int r = w + dy;
            const v8s bf = *(const v8s*)&F[((kb * RR + r) * JJ + i_px) * 8];
            acc0[dy] = __builtin_amdgcn_mfma_f32_16x16x32_bf16(afrag, bf, acc0[dy], 0, 0, 0);
        }
        // tile1 packed: pair P covers dy=2P (cols n<8) and dy=2P+1 (n>=8)
        #pragma unroll
        for (int P = 0; P < 5; ++P) {
            int r = w + 2 * P + (i_px >> 3);
            if (r > RR - 1) r = RR - 1;       // P=4 upper half unused
            const int j = 16 + (i_px & 7);
            const v8s bf = *(const v8s*)&F[((kb * RR + r) * JJ + j) * 8];
            acc1[P] = __builtin_amdgcn_mfma_f32_16x16x32_bf16(afrag, bf, acc1[P], 0, 0, 0);
        }

        if (k < NCH - 1) {
            #pragma unroll
            for (int e = 0; e < 8; ++e) a_cur[e] = a_nxt[e];
        }
    }

    // ---- epilogue: diagonal extract via wave-private LDS scratch ----
    BARRIER();                         // all waves done with F as B operand
    float* epw = (float*)F + w * (16 * 24);   // 1.5 KB per wave
    const int g = lane >> 4;

    for (int dy = 0; dy < ND; ++dy) {
        #pragma unroll
        for (int q = 0; q < 4; ++q)
            epw[(g * 4 + q) * 24 + i_px] = acc0[dy][q];
        if ((i_px >> 3) == (dy & 1)) {
            #pragma unroll
            for (int q = 0; q < 4; ++q)
                epw[(g * 4 + q) * 24 + 16 + (i_px & 7)] = acc1[dy >> 1][q];
        }
        LGKM0();
        #pragma unroll
        for (int rep = 0; rep < 3; ++rep) {
            const int dx = g + rep * 4;
            if (dx < 9) {
                const float v = epw[i_px * 24 + i_px + dx] * (1.0f / 256.0f);
                out[((((long)b * 81) + dy * 9 + dx) * H_ + (y0 + w)) * W_ + x0 + i_px] = v;
            }
        }
        LGKM0();
    }
}

extern "C" void kernel_launch(void* const* d_in, const int* in_sizes, int n_in,
                              void* d_out, int out_size, void* d_ws, size_t ws_size,
                              hipStream_t stream) {
    const float* in1 = (const float*)d_in[0];
    const float* in2 = (const float*)d_in[1];
    float* outp      = (float*)d_out;
    dim3 grid(W_ / TW, H_ / TY, B_);   // (8, 16, 8) = 1024 blocks
    corr_mfma_kernel<<<grid, 512, 0, stream>>>(in1, in2, outp);
}

// Round 4
// 108.767 us; speedup vs baseline: 1.7428x; 1.2109x over previous
//
#include <hip/hip_runtime.h>
#include <stdint.h>

// Correlation layer: in1,in2 [8,256,128,128] f32 -> out [8,81,128,128] f32
// out[b, dy*9+dx, y, x] = mean_c in1[b,c,y,x] * in2pad[b,c,y+dy,x+dx], pad=4
//
// v4: double-buffered f32 DMA stage (global_load_lds) + counted vmcnt(6) so
// the next chunk's 48KB is ALWAYS in flight (never drain to 0 mid-loop).
// 120KB dynamic LDS -> 1 block/CU; HBM kept continuously busy.
// XCD swizzle: batch==XCD, y-fastest within XCD for halo L2 reuse.

#define B_  8
#define C_  256
#define H_  128
#define W_  128
#define ND  9
#define TY  8
#define TW  16
#define KC  32
#define KB  4                    // KC/8
#define RR  16                   // TY+8
#define JJ  24
#define NITEM 3                  // convert items per thread
#define NDMA  6                  // DMA issues per wave per chunk
#define CS   (H_ * W_)
#define NCH  (C_ / KC)           // 8 chunks
#define SBUF (KC * RR * JJ)      // 12288 floats per S buffer (48KB)
#define FOFF (2 * SBUF * 4)      // byte offset of F (98304)
#define LDS_TOTAL (FOFF + KB * RR * JJ * 8 * 2)   // 122880 bytes

typedef short v8s __attribute__((ext_vector_type(8)));
typedef float v4f __attribute__((ext_vector_type(4)));

__device__ __forceinline__ unsigned short f2bf(float f) {
    union { float f; unsigned u; } v; v.f = f;
    return (unsigned short)((v.u + 0x7FFFu + ((v.u >> 16) & 1u)) >> 16);
}

__device__ __forceinline__ void dma16(const float* g, void* lds) {
    __builtin_amdgcn_global_load_lds(
        (const __attribute__((address_space(1))) void*)g,
        (__attribute__((address_space(3))) void*)lds, 16, 0, 0);
}

#define FENCE()        asm volatile("" ::: "memory")
// counted wait: keep the 6 newest (next chunk's DMA) in flight
#define WAITV6_BAR()   asm volatile("s_waitcnt vmcnt(6) lgkmcnt(0)\n\ts_barrier" ::: "memory")
#define WAITV0_BAR()   asm volatile("s_waitcnt vmcnt(0) lgkmcnt(0)\n\ts_barrier" ::: "memory")
#define LGKM0_BAR()    asm volatile("s_waitcnt lgkmcnt(0)\n\ts_barrier" ::: "memory")
#define LGKM0()        asm volatile("s_waitcnt lgkmcnt(0)" ::: "memory")

__global__ __launch_bounds__(512, 2)
void corr_mfma_kernel(const float* __restrict__ in1,
                      const float* __restrict__ in2,
                      float* __restrict__ out) {
    extern __shared__ __align__(16) char ldsbase[];
    float* S = (float*)ldsbase;                 // S[2][KC][RR][JJ]
    short* F = (short*)(ldsbase + FOFF);        // F[KB][RR][JJ][8]

    const int tid  = threadIdx.x;
    const int lane = tid & 63;
    const int w    = tid >> 6;

    // XCD swizzle: batch == XCD id (8 batches, 8 XCDs); y fastest within XCD
    const int lin = blockIdx.x;                 // 0..1023
    const int b   = lin & 7;
    const int idx = lin >> 3;                   // 0..127
    const int by  = idx & 15;
    const int bx  = idx >> 4;
    const int x0  = bx * TW;
    const int y0  = by * TY;

    const int i_px = lane & 15;
    const int kb   = lane >> 4;

    // ---- DMA descriptors (chunk 0 addresses; advance by KC*CS per chunk) ----
    const float* dsrc[NDMA];
    int ddst[NDMA];                             // LDS byte offset within one S buffer
    #pragma unroll
    for (int t = 0; t < NDMA; ++t) {
        const int q  = w * NDMA + t;            // wave-uniform
        const int g  = q * 64 + lane;
        const int cc = g / 96;
        const int rm = g % 96;
        const int r  = rm / 6;
        const int jg = rm % 6;
        int gy = y0 - 4 + r;
        int gx = x0 - 4 + jg * 4;
        gy = gy < 0 ? 0 : (gy > H_ - 1 ? H_ - 1 : gy);
        gx = gx < 0 ? 0 : (gx > W_ - 4 ? W_ - 4 : gx);
        dsrc[t] = in2 + ((long)(b * C_ + cc) * H_ + gy) * W_ + gx;
        ddst[t] = q * 1024;                     // wave-uniform LDS base
    }

    // ---- convert-pass descriptors ----
    int soff[NITEM], foff[NITEM];
    bool valid[NITEM];
    #pragma unroll
    for (int it = 0; it < NITEM; ++it) {
        const int s   = tid + it * 512;
        const int ikb = s / (RR * JJ);
        const int ir  = (s / JJ) % RR;
        const int ij  = s % JJ;
        soff[it]  = ikb * 8 * (RR * JJ) + ir * JJ + ij;
        foff[it]  = s * 8;
        valid[it] = ((unsigned)(y0 - 4 + ir) < (unsigned)H_) &&
                    ((unsigned)(x0 - 4 + ij) < (unsigned)W_);
    }

    const float* p1 =
        in1 + (((long)b * C_ + kb * 8) * H_ + (y0 + w)) * W_ + x0 + i_px;

    v4f acc0[ND];
    v4f acc1[5];
    #pragma unroll
    for (int d = 0; d < ND; ++d) acc0[d] = (v4f)0.0f;
    #pragma unroll
    for (int p = 0; p < 5; ++p)  acc1[p] = (v4f)0.0f;

    // ---- prologue: A(0) loads, then DMA(0) -> S[0] ----
    float a_cur[8], a_nxt[8];
    #pragma unroll
    for (int e = 0; e < 8; ++e) a_cur[e] = p1[(long)e * CS];
    FENCE();
    #pragma unroll
    for (int t = 0; t < NDMA; ++t) dma16(dsrc[t], (char*)S + ddst[t]);

    #pragma unroll
    for (int k = 0; k < NCH; ++k) {
        const int pb = k & 1;                   // current S buffer

        // (1) consume a_cur -> afrag (compiler waits A(k) with counted vmcnt)
        v8s afrag;
        #pragma unroll
        for (int e = 0; e < 8; ++e) afrag[e] = (short)f2bf(a_cur[e]);

        // (2) issue next chunk: A(k+1) loads, then DMA(k+1) -> S[pb^1]
        if (k < NCH - 1) {
            const long co = (long)(k + 1) * KC * CS;
            #pragma unroll
            for (int e = 0; e < 8; ++e) a_nxt[e] = p1[co + (long)e * CS];
            FENCE();
            #pragma unroll
            for (int t = 0; t < NDMA; ++t)
                dma16(dsrc[t] + co, (char*)S + (pb ^ 1) * (SBUF * 4) + ddst[t]);
            // (3) retire DMA(k)+A(k+1); keep DMA(k+1) (6 newest) in flight
            WAITV6_BAR();
        } else {
            WAITV0_BAR();
        }

        // (4) convert S[pb] (f32) -> F (bf16 fragment order)
        v8s pk[NITEM];
        #pragma unroll
        for (int it = 0; it < NITEM; ++it) {
            #pragma unroll
            for (int e = 0; e < 8; ++e)
                pk[it][e] = (short)f2bf(S[pb * SBUF + soff[it] + e * (RR * JJ)]);
            if (!valid[it]) pk[it] = (v8s)0;
        }
        #pragma unroll
        for (int it = 0; it < NITEM; ++it)
            *(v8s*)&F[foff[it]] = pk[it];

        // (5) F visible to all waves
        LGKM0_BAR();

        // (6) MFMAs: tile0 9 dy
        #pragma unroll
        for (int dy = 0; dy < ND; ++dy) {
            const int r = w + dy;
            const v8s bf = *(const v8s*)&F[((kb * RR + r) * JJ + i_px) * 8];
            acc0[dy] = __builtin_amdgcn_mfma_f32_16x16x32_bf16(afrag, bf, acc0[dy], 0, 0, 0);
        }
        // tile1 packed: pair P covers dy=2P (cols n<8) and dy=2P+1 (n>=8)
        #pragma unroll
        for (int P = 0; P < 5; ++P) {
            int r = w + 2 * P + (i_px >> 3);
            if (r > RR - 1) r = RR - 1;         // P=4 upper half unused
            const int j = 16 + (i_px & 7);
            const v8s bf = *(const v8s*)&F[((kb * RR + r) * JJ + j) * 8];
            acc1[P] = __builtin_amdgcn_mfma_f32_16x16x32_bf16(afrag, bf, acc1[P], 0, 0, 0);
        }

        if (k < NCH - 1) {
            #pragma unroll
            for (int e = 0; e < 8; ++e) a_cur[e] = a_nxt[e];
        }
    }

    // ---- epilogue: diagonal extract via wave-private LDS scratch ----
    LGKM0_BAR();                       // all waves done with F as B operand
    float* epw = (float*)F + w * (16 * 24);
    const int g = lane >> 4;

    for (int dy = 0; dy < ND; ++dy) {
        #pragma unroll
        for (int q = 0; q < 4; ++q)
            epw[(g * 4 + q) * 24 + i_px] = acc0[dy][q];
        if ((i_px >> 3) == (dy & 1)) {
            #pragma unroll
            for (int q = 0; q < 4; ++q)
                epw[(g * 4 + q) * 24 + 16 + (i_px & 7)] = acc1[dy >> 1][q];
        }
        LGKM0();
        #pragma unroll
        for (int rep = 0; rep < 3; ++rep) {
            const int dx = g + rep * 4;
            if (dx < 9) {
                const float v = epw[i_px * 24 + i_px + dx] * (1.0f / 256.0f);
                out[((((long)b * 81) + dy * 9 + dx) * H_ + (y0 + w)) * W_ + x0 + i_px] = v;
            }
        }
        LGKM0();
    }
}

extern "C" void kernel_launch(void* const* d_in, const int* in_sizes, int n_in,
                              void* d_out, int out_size, void* d_ws, size_t ws_size,
                              hipStream_t stream) {
    const float* in1 = (const float*)d_in[0];
    const float* in2 = (const float*)d_in[1];
    float* outp      = (float*)d_out;
    // >64KB dynamic LDS needs the attribute; idempotent, graph-capture-safe
    (void)hipFuncSetAttribute((const void*)corr_mfma_kernel,
                              hipFuncAttributeMaxDynamicSharedMemorySize,
                              LDS_TOTAL);
    corr_mfma_kernel<<<1024, 512, LDS_TOTAL, stream>>>(in1, in2, outp);
}

// Round 6
// 96.021 us; speedup vs baseline: 1.9741x; 1.1327x over previous
//
#include <hip/hip_runtime.h>
#include <stdint.h>

// Correlation layer: in1,in2 [8,256,128,128] f32 -> out [8,81,128,128] f32
// out[b, dy*9+dx, y, x] = mean_c in1[b,c,y,x] * in2pad[b,c,y+dy,x+dx], pad=4
//
// v6 = v5 with the cross-wave race fixed: vmcnt waits are per-wave, so every
// convert (reads whole S buffer incl. other waves' DMA) must be preceded by
// wait+S_BARRIER, and every MFMA phase by lgkm+S_BARRIER after convert.
// Schedule/chunk: [issue DMA(k+2)+A(k+2); MFMA(k); vmcnt(14)+bar] [convert(k+1); lgkm+bar]
// Mid-loop waits keep the newest 14 (6 DMA + 8 A) in flight -> HBM never idles.

#define B_  8
#define C_  256
#define H_  128
#define W_  128
#define ND  9
#define TY  8
#define TW  16
#define KC  32
#define KB  4                    // KC/8
#define RR  16                   // TY+8
#define JJ  24
#define NITEM 3                  // convert items per thread
#define NDMA  6                  // DMA issues per wave per chunk
#define CS   (H_ * W_)
#define NCH  (C_ / KC)           // 8 chunks
#define SBUF (KC * RR * JJ)      // floats per S buffer (48KB)
#define FBUF (KB * RR * JJ * 8)  // shorts per F buffer (24KB)
#define FOFF (2 * SBUF * 4)      // byte offset of F area
#define LDS_TOTAL (FOFF + 2 * FBUF * 2)   // 147456 bytes

typedef short v8s __attribute__((ext_vector_type(8)));
typedef float v4f __attribute__((ext_vector_type(4)));

__device__ __forceinline__ unsigned short f2bf(float f) {
    union { float f; unsigned u; } v; v.f = f;
    return (unsigned short)((v.u + 0x7FFFu + ((v.u >> 16) & 1u)) >> 16);
}

__device__ __forceinline__ void dma16(const float* g, void* lds) {
    __builtin_amdgcn_global_load_lds(
        (const __attribute__((address_space(1))) void*)g,
        (__attribute__((address_space(3))) void*)lds, 16, 0, 0);
}

#define FENCE()        asm volatile("" ::: "memory")
// wait + BARRIER fused: rendezvous is mandatory (vmcnt is per-wave!)
#define WAITV14_BAR()  asm volatile("s_waitcnt vmcnt(14)\n\ts_barrier" ::: "memory")
#define WAITV0_BAR()   asm volatile("s_waitcnt vmcnt(0)\n\ts_barrier" ::: "memory")
#define LGKM0_BAR()    asm volatile("s_waitcnt lgkmcnt(0)\n\ts_barrier" ::: "memory")
#define LGKM0()        asm volatile("s_waitcnt lgkmcnt(0)" ::: "memory")

__global__ __launch_bounds__(512, 2)
void corr_mfma_kernel(const float* __restrict__ in1,
                      const float* __restrict__ in2,
                      float* __restrict__ out) {
    extern __shared__ __align__(16) char ldsbase[];
    float* S = (float*)ldsbase;                 // S[2][KC][RR][JJ]
    short* F = (short*)(ldsbase + FOFF);        // F[2][KB][RR][JJ][8]

    const int tid  = threadIdx.x;
    const int lane = tid & 63;
    const int w    = tid >> 6;

    // XCD swizzle: batch == XCD id; y fastest within XCD (halo co-residency)
    const int lin = blockIdx.x;
    const int b   = lin & 7;
    const int idx = lin >> 3;
    const int by  = idx & 15;
    const int bx  = idx >> 4;
    const int x0  = bx * TW;
    const int y0  = by * TY;

    const int i_px = lane & 15;
    const int kb   = lane >> 4;

    // ---- DMA descriptors (chunk-0 addresses) ----
    const float* dsrc[NDMA];
    int ddst[NDMA];
    #pragma unroll
    for (int t = 0; t < NDMA; ++t) {
        const int q  = w * NDMA + t;            // wave-uniform
        const int g  = q * 64 + lane;
        const int cc = g / 96;
        const int rm = g % 96;
        const int r  = rm / 6;
        const int jg = rm % 6;
        int gy = y0 - 4 + r;
        int gx = x0 - 4 + jg * 4;
        gy = gy < 0 ? 0 : (gy > H_ - 1 ? H_ - 1 : gy);
        gx = gx < 0 ? 0 : (gx > W_ - 4 ? W_ - 4 : gx);
        dsrc[t] = in2 + ((long)(b * C_ + cc) * H_ + gy) * W_ + gx;
        ddst[t] = q * 1024;
    }

    // ---- convert-pass descriptors ----
    int soff[NITEM], foff[NITEM];
    bool valid[NITEM];
    #pragma unroll
    for (int it = 0; it < NITEM; ++it) {
        const int s   = tid + it * 512;
        const int ikb = s / (RR * JJ);
        const int ir  = (s / JJ) % RR;
        const int ij  = s % JJ;
        soff[it]  = ikb * 8 * (RR * JJ) + ir * JJ + ij;
        foff[it]  = s * 8;
        valid[it] = ((unsigned)(y0 - 4 + ir) < (unsigned)H_) &&
                    ((unsigned)(x0 - 4 + ij) < (unsigned)W_);
    }

    const float* p1 =
        in1 + (((long)b * C_ + kb * 8) * H_ + (y0 + w)) * W_ + x0 + i_px;

    v4f acc0[ND];
    v4f acc1[5];
    #pragma unroll
    for (int d = 0; d < ND; ++d) acc0[d] = (v4f)0.0f;
    #pragma unroll
    for (int p = 0; p < 5; ++p)  acc1[p] = (v4f)0.0f;

    float a_buf[2][8];
    v8s afrag, afrag_nxt;

    // ---- prologue ----
    #pragma unroll
    for (int t = 0; t < NDMA; ++t) dma16(dsrc[t], (char*)S + ddst[t]);
    #pragma unroll
    for (int e = 0; e < 8; ++e) a_buf[0][e] = p1[(long)e * CS];
    FENCE();
    #pragma unroll
    for (int t = 0; t < NDMA; ++t)
        dma16(dsrc[t] + (long)KC * CS, (char*)S + SBUF * 4 + ddst[t]);
    #pragma unroll
    for (int e = 0; e < 8; ++e) a_buf[1][e] = p1[(long)KC * CS + (long)e * CS];
    FENCE();
    WAITV14_BAR();                   // ALL waves' DMA(0) landed; DMA(1)+A(1) in flight
    #pragma unroll
    for (int e = 0; e < 8; ++e) afrag[e] = (short)f2bf(a_buf[0][e]);
    {
        v8s pk[NITEM];
        #pragma unroll
        for (int it = 0; it < NITEM; ++it) {
            #pragma unroll
            for (int e = 0; e < 8; ++e)
                pk[it][e] = (short)f2bf(S[soff[it] + e * (RR * JJ)]);
            if (!valid[it]) pk[it] = (v8s)0;
        }
        #pragma unroll
        for (int it = 0; it < NITEM; ++it)
            *(v8s*)&F[foff[it]] = pk[it];
    }
    LGKM0_BAR();                     // F(0) visible to all waves

    // ---- main pipeline ----
    #pragma unroll
    for (int k = 0; k < NCH; ++k) {
        const int cb = k & 1;

        // Region A: issue chunk k+2; MFMA chunk k; rendezvous on DMA(k+1)
        if (k + 2 < NCH) {
            const long co = (long)(k + 2) * KC * CS;
            #pragma unroll
            for (int t = 0; t < NDMA; ++t)
                dma16(dsrc[t] + co, (char*)S + cb * (SBUF * 4) + ddst[t]);
            #pragma unroll
            for (int e = 0; e < 8; ++e) a_buf[cb][e] = p1[co + (long)e * CS];
            FENCE();
        }

        #pragma unroll
        for (int dy = 0; dy < ND; ++dy) {
            const int r = w + dy;
            const v8s bf = *(const v8s*)&F[cb * FBUF + ((kb * RR + r) * JJ + i_px) * 8];
            acc0[dy] = __builtin_amdgcn_mfma_f32_16x16x32_bf16(afrag, bf, acc0[dy], 0, 0, 0);
        }
        #pragma unroll
        for (int P = 0; P < 5; ++P) {
            int r = w + 2 * P + (i_px >> 3);
            if (r > RR - 1) r = RR - 1;
            const int j = 16 + (i_px & 7);
            const v8s bf = *(const v8s*)&F[cb * FBUF + ((kb * RR + r) * JJ + j) * 8];
            acc1[P] = __builtin_amdgcn_mfma_f32_16x16x32_bf16(afrag, bf, acc1[P], 0, 0, 0);
        }

        if (k + 1 < NCH) {
            // all waves' DMA(k+1) landed; chunk k+2 (14 newest) stays in flight
            if (k + 2 < NCH) { WAITV14_BAR(); } else { WAITV0_BAR(); }

            // Region B: convert chunk k+1, then make F(k+1) visible
            #pragma unroll
            for (int e = 0; e < 8; ++e) afrag_nxt[e] = (short)f2bf(a_buf[cb ^ 1][e]);
            v8s pk[NITEM];
            #pragma unroll
            for (int it = 0; it < NITEM; ++it) {
                #pragma unroll
                for (int e = 0; e < 8; ++e)
                    pk[it][e] = (short)f2bf(S[(cb ^ 1) * SBUF + soff[it] + e * (RR * JJ)]);
                if (!valid[it]) pk[it] = (v8s)0;
            }
            #pragma unroll
            for (int it = 0; it < NITEM; ++it)
                *(v8s*)&F[(cb ^ 1) * FBUF + foff[it]] = pk[it];
            afrag = afrag_nxt;

            LGKM0_BAR();
        }
    }

    // ---- epilogue: diagonal extract via wave-private LDS scratch ----
    LGKM0_BAR();                     // all waves past their last F reads
    float* epw = (float*)F + w * (16 * 24);
    const int g = lane >> 4;

    for (int dy = 0; dy < ND; ++dy) {
        #pragma unroll
        for (int q = 0; q < 4; ++q)
            epw[(g * 4 + q) * 24 + i_px] = acc0[dy][q];
        if ((i_px >> 3) == (dy & 1)) {
            #pragma unroll
            for (int q = 0; q < 4; ++q)
                epw[(g * 4 + q) * 24 + 16 + (i_px & 7)] = acc1[dy >> 1][q];
        }
        LGKM0();
        #pragma unroll
        for (int rep = 0; rep < 3; ++rep) {
            const int dx = g + rep * 4;
            if (dx < 9) {
                const float v = epw[i_px * 24 + i_px + dx] * (1.0f / 256.0f);
                out[((((long)b * 81) + dy * 9 + dx) * H_ + (y0 + w)) * W_ + x0 + i_px] = v;
            }
        }
        LGKM0();
    }
}

extern "C" void kernel_launch(void* const* d_in, const int* in_sizes, int n_in,
                              void* d_out, int out_size, void* d_ws, size_t ws_size,
                              hipStream_t stream) {
    const float* in1 = (const float*)d_in[0];
    const float* in2 = (const float*)d_in[1];
    float* outp      = (float*)d_out;
    (void)hipFuncSetAttribute((const void*)corr_mfma_kernel,
                              hipFuncAttributeMaxDynamicSharedMemorySize,
                              LDS_TOTAL);
    corr_mfma_kernel<<<1024, 512, LDS_TOTAL, stream>>>(in1, in2, outp);
}